// Round 4
// baseline (156.422 us; speedup 1.0000x reference)
//
#include <hip/hip_runtime.h>

#define DIM  128
#define HID  32
#define KTOT 384          // 3*DIM
#define TPW  16           // edges per wave-tile

typedef __attribute__((ext_vector_type(4))) float f32x4;
typedef __attribute__((ext_vector_type(2))) float f32x2;
typedef __attribute__((ext_vector_type(8))) int   i32x8;

// fp8 e4m3 (OCP on gfx950) pack via HW converts
static __device__ __forceinline__ unsigned pk4_fp8(float a, float b, float c, float d) {
    unsigned r = __builtin_amdgcn_cvt_pk_fp8_f32(a, b, 0u, false);
    return __builtin_amdgcn_cvt_pk_fp8_f32(c, d, r, true);
}

// elementwise product of two 32-byte fp8 vectors (8 dwords), result fp8
static __device__ __forceinline__ i32x8 prod_fp8x32(i32x8 a, i32x8 b) {
    i32x8 r;
#pragma unroll
    for (int j = 0; j < 8; j++) {
        unsigned av = (unsigned)a[j], bv = (unsigned)b[j];
        f32x2 a0 = __builtin_amdgcn_cvt_pk_f32_fp8(av, false);
        f32x2 a1 = __builtin_amdgcn_cvt_pk_f32_fp8(av, true);
        f32x2 b0 = __builtin_amdgcn_cvt_pk_f32_fp8(bv, false);
        f32x2 b1 = __builtin_amdgcn_cvt_pk_f32_fp8(bv, true);
        f32x2 p0 = a0 * b0, p1 = a1 * b1;
        unsigned pr = __builtin_amdgcn_cvt_pk_fp8_f32(p0.x, p0.y, 0u, false);
        pr = __builtin_amdgcn_cvt_pk_fp8_f32(p1.x, p1.y, pr, true);
        r[j] = (int)pr;
    }
    return r;
}

// 32-byte (8-dword) load as two dwordx4
static __device__ __forceinline__ i32x8 ld32(const unsigned char* p) {
    int4 lo = *(const int4*)p;
    int4 hi = *(const int4*)(p + 16);
    i32x8 v;
    v[0] = lo.x; v[1] = lo.y; v[2] = lo.z; v[3] = lo.w;
    v[4] = hi.x; v[5] = hi.y; v[6] = hi.z; v[7] = hi.w;
    return v;
}

// ---------------------------------------------------------------------------
// Kernel 0: wsum[r] = sum_d W[r][d], f32, 32 blocks x 4 rows (wave per row).
// (einsum 'ed,ef->e' factorizes: bilinear[e] = (z_src.wsum)*(sum z_dst))
// ---------------------------------------------------------------------------
__global__ __launch_bounds__(256) void wsum_kernel(const float* __restrict__ W,
                                                   float* __restrict__ wsum)
{
    const int wv = threadIdx.x >> 6, lane = threadIdx.x & 63;
    const int r = blockIdx.x * 4 + wv;            // 0..127
    float2 v = *(const float2*)(W + (size_t)r * DIM + lane * 2);
    float s = v.x + v.y;
    s += __shfl_xor(s, 1);  s += __shfl_xor(s, 2);  s += __shfl_xor(s, 4);
    s += __shfl_xor(s, 8);  s += __shfl_xor(s, 16); s += __shfl_xor(s, 32);
    if (lane == 0) wsum[r] = s;
}

// ---------------------------------------------------------------------------
// Kernel 1 prep: blocks [0,nNodeBlk): half-wave per node —
//   zb8[n][:] = fp8(z[n][:]), s1[n] = z.wsum (f32), s2[n] = sum z (f32)
// blocks [nNodeBlk, +48): w1T8[h][k] = fp8(w1[k][h])  (384x32 transpose)
// ---------------------------------------------------------------------------
__global__ __launch_bounds__(256) void prep_kernel(
    const float* __restrict__ z, const float* __restrict__ w1,
    const float* __restrict__ wsum,
    unsigned char* __restrict__ zb8, unsigned char* __restrict__ w1T8,
    float* __restrict__ s1, float* __restrict__ s2,
    int nNodes, int nNodeBlk)
{
    const int b = blockIdx.x;
    const int tid = threadIdx.x;
    if (b < nNodeBlk) {
        const int n = b * 8 + (tid >> 5);
        const int l32 = tid & 31;
        if (n >= nNodes) return;                   // half-wave-uniform exit

        float4 v = *(const float4*)(z + (size_t)n * DIM + l32 * 4);
        float4 w = *(const float4*)(wsum + l32 * 4);

        float a1 = v.x * w.x + v.y * w.y + v.z * w.z + v.w * w.w;
        float a2 = v.x + v.y + v.z + v.w;

        *(unsigned*)(zb8 + (size_t)n * DIM + l32 * 4) = pk4_fp8(v.x, v.y, v.z, v.w);

        a1 += __shfl_xor(a1, 1);  a1 += __shfl_xor(a1, 2);  a1 += __shfl_xor(a1, 4);
        a1 += __shfl_xor(a1, 8);  a1 += __shfl_xor(a1, 16);
        a2 += __shfl_xor(a2, 1);  a2 += __shfl_xor(a2, 2);  a2 += __shfl_xor(a2, 4);
        a2 += __shfl_xor(a2, 8);  a2 += __shfl_xor(a2, 16);
        if (l32 == 0) { s1[n] = a1; s2[n] = a2; }
    } else {
        const int idx = (b - nNodeBlk) * 256 + tid;    // 0..12287 exact (48 blocks)
        const int k = idx >> 5, h = idx & 31;
        unsigned r = __builtin_amdgcn_cvt_pk_fp8_f32(w1[idx], 0.f, 0u, false);
        w1T8[(size_t)h * KTOT + k] = (unsigned char)(r & 0xff);
    }
}

// ---------------------------------------------------------------------------
// Kernel 2: edge kernel — exact R0/R1 structure (proven 128.0 us config).
// R11 PROBE ROUND: this kernel is launched TWICE with identical args; the
// second pass writes identical values (idempotent). Total time = base + E,
// isolating the edge kernel's true duration E, which the top-5 profile view
// (saturated by 42us harness poison fills) cannot show.
// ---------------------------------------------------------------------------
__global__ __launch_bounds__(256, 2) void edge_kernel(
    const unsigned char* __restrict__ zb8, const int* __restrict__ ei,
    const float* __restrict__ s1, const float* __restrict__ s2,
    const unsigned char* __restrict__ w1T8, const float* __restrict__ b1,
    const float* __restrict__ w2, const float* __restrict__ b2,
    const float* __restrict__ bias, float* __restrict__ out,
    int nE, int nTiles)
{
    const int lane = threadIdx.x & 63;
    const int wv   = threadIdx.x >> 6;
    const int l15  = lane & 15;
    const int quad = lane >> 4;
    const int sOne = 0x7F7F7F7F;                  // e8m0 1.0 in every byte

    int t = blockIdx.x * 4 + wv;
    const int nW = gridDim.x * 4;
    if (t >= nTiles) return;

    // B fragments: chunk c covers k=[c*128,(c+1)*128); lane (l15=h-col, quad)
    // holds 32 contiguous k at quad*32. 6 x i32x8 = 48 VGPRs.
    i32x8 B0[3], B1[3];
    {
        const unsigned char* b0p = w1T8 + (size_t)l15 * KTOT + quad * 32;
        const unsigned char* b1p = w1T8 + (size_t)(16 + l15) * KTOT + quad * 32;
#pragma unroll
        for (int c = 0; c < 3; c++) {
            B0[c] = ld32(b0p + c * 128);
            B1[c] = ld32(b1p + c * 128);
        }
    }
    const float b1a = b1[l15],      w2a = w2[l15];
    const float b1b = b1[16 + l15], w2b = w2[16 + l15];
    const float cbias = bias[0] + b2[0];

    for (; t < nTiles; t += nW) {
        const int e = t * TPW + l15;
        int s_ = 0, d_ = 0;
        if (e < nE) { s_ = ei[e]; d_ = ei[nE + e]; }
        const float bil = s1[s_] * s2[d_];         // f32 path, lane l15 = edge l15

        // rows: lane (l15=edge, quad) loads 32B at quad*32 -> 2 dwordx4 each
        i32x8 zs8 = ld32(zb8 + (size_t)s_ * DIM + quad * 32);
        i32x8 zd8 = ld32(zb8 + (size_t)d_ * DIM + quad * 32);

        f32x4 acc0 = {0.f, 0.f, 0.f, 0.f};
        f32x4 acc1 = {0.f, 0.f, 0.f, 0.f};
        // chunk 0: zs (K 0..127)
        acc0 = __builtin_amdgcn_mfma_scale_f32_16x16x128_f8f6f4(
                   zs8, B0[0], acc0, 0, 0, 0, sOne, 0, sOne);
        acc1 = __builtin_amdgcn_mfma_scale_f32_16x16x128_f8f6f4(
                   zs8, B1[0], acc1, 0, 0, 0, sOne, 0, sOne);
        // chunk 1: zd (K 128..255)
        acc0 = __builtin_amdgcn_mfma_scale_f32_16x16x128_f8f6f4(
                   zd8, B0[1], acc0, 0, 0, 0, sOne, 0, sOne);
        acc1 = __builtin_amdgcn_mfma_scale_f32_16x16x128_f8f6f4(
                   zd8, B1[1], acc1, 0, 0, 0, sOne, 0, sOne);
        // chunk 2: zs*zd (K 256..383)
        i32x8 p8 = prod_fp8x32(zs8, zd8);
        acc0 = __builtin_amdgcn_mfma_scale_f32_16x16x128_f8f6f4(
                   p8, B0[2], acc0, 0, 0, 0, sOne, 0, sOne);
        acc1 = __builtin_amdgcn_mfma_scale_f32_16x16x128_f8f6f4(
                   p8, B1[2], acc1, 0, 0, 0, sOne, 0, sOne);

        // epilogue (validated R3..R8): C/D col=l15 (h), row=quad*4+r (edge)
        const int e0 = t * TPW;
#pragma unroll
        for (int r = 0; r < 4; r++) {
            float v = fmaxf(acc0[r] + b1a, 0.f) * w2a
                    + fmaxf(acc1[r] + b1b, 0.f) * w2b;
            v += __shfl_xor(v, 1); v += __shfl_xor(v, 2);
            v += __shfl_xor(v, 4); v += __shfl_xor(v, 8);
            const int eL = quad * 4 + r;
            const float bilr = __shfl(bil, eL);    // bil replicated across quads
            if (l15 == r && (e0 + eL) < nE)
                out[e0 + eL] = v + bilr + cbias;
        }
    }
}

// ---------------------------------------------------------------------------
// Workspace: zb8 uchar[nNodes*128] | s1 f32[nNodes] | s2 f32[nNodes]
//          | wsum f32[128] | w1T8 uchar[32*384]        (~13.7 MB)
// ---------------------------------------------------------------------------
extern "C" void kernel_launch(void* const* d_in, const int* in_sizes, int n_in,
                              void* d_out, int out_size, void* d_ws, size_t ws_size,
                              hipStream_t stream)
{
    const float* z    = (const float*)d_in[0];
    const int*   ei   = (const int*)d_in[1];
    const float* W    = (const float*)d_in[2];
    const float* bias = (const float*)d_in[3];
    const float* w1   = (const float*)d_in[4];
    const float* b1   = (const float*)d_in[5];
    const float* w2   = (const float*)d_in[6];
    const float* b2   = (const float*)d_in[7];
    float* out = (float*)d_out;

    const int nNodes = in_sizes[0] / DIM;
    const int nE = out_size;

    unsigned char* zb8 = (unsigned char*)d_ws;
    float* s1   = (float*)(zb8 + (size_t)nNodes * DIM);
    float* s2   = s1 + nNodes;
    float* wsum = s2 + nNodes;
    unsigned char* w1T8 = (unsigned char*)(wsum + DIM);

    wsum_kernel<<<32, 256, 0, stream>>>(W, wsum);

    const int nNodeBlk = (nNodes + 7) / 8;
    prep_kernel<<<nNodeBlk + 48, 256, 0, stream>>>(z, w1, wsum, zb8, w1T8,
                                                   s1, s2, nNodes, nNodeBlk);

    const int nTiles = (nE + TPW - 1) / TPW;
    int grid = 1024;
    if (grid * 4 > nTiles) grid = (nTiles + 3) / 4;
    edge_kernel<<<grid, 256, 0, stream>>>(zb8, ei, s1, s2, w1T8,
                                          b1, w2, b2, bias, out, nE, nTiles);
    // PROBE: identical second pass (idempotent writes). Total = base + E.
    // Remove next round once E is known.
    edge_kernel<<<grid, 256, 0, stream>>>(zb8, ei, s1, s2, w1T8,
                                          b1, w2, b2, bias, out, nE, nTiles);
}

// Round 5
// 127.109 us; speedup vs baseline: 1.2306x; 1.2306x over previous
//
#include <hip/hip_runtime.h>

#define DIM  128
#define HID  32
#define KTOT 384          // 3*DIM
#define TPW  16           // edges per wave-tile

typedef __attribute__((ext_vector_type(4))) float f32x4;
typedef __attribute__((ext_vector_type(2))) float f32x2;
typedef __attribute__((ext_vector_type(8))) int   i32x8;

#if __has_builtin(__builtin_amdgcn_cvt_scalef32_pk_f32_fp4)
#define HW_FP4_DEC 1
#else
#define HW_FP4_DEC 0
#endif

// ---- fp4 e2m1 helpers -----------------------------------------------------
// encode f32 -> e2m1 nibble, round-to-nearest (ties up). values:
// {0,0.5,1,1.5,2,3,4,6} x sign. Manual (no builtin dependency); prep-side only.
static __device__ __forceinline__ unsigned enc_fp4(float x) {
    unsigned s = (x < 0.f) ? 8u : 0u;
    float a = fabsf(x);
    unsigned m = (a >= 0.25f) + (a >= 0.75f) + (a >= 1.25f) + (a >= 1.75f)
               + (a >= 2.5f)  + (a >= 3.5f)  + (a >= 5.0f);
    return s | m;
}

// manual decode fallback: nibble -> f32
static __device__ __forceinline__ float dec_fp4(unsigned nib) {
    unsigned m = nib & 7u;
    float v = __uint_as_float(((126u + (m >> 1)) << 23) | ((m & 1u) << 22));
    if (m < 2u) v = (float)m * 0.5f;       // 0, 0.5 (denormal grid points)
    return (nib & 8u) ? -v : v;
}

// fp8 e4m3 pack via HW converts (validated path)
static __device__ __forceinline__ unsigned pk4_fp8(float a, float b, float c, float d) {
    unsigned r = __builtin_amdgcn_cvt_pk_fp8_f32(a, b, 0u, false);
    return __builtin_amdgcn_cvt_pk_fp8_f32(c, d, r, true);
}

// elementwise product of two 16-byte fp4 rows (32 elems) -> fp8-packed i32x8.
// k-order preserved: fp4 nibble j of dword i  ->  fp8 byte (8i+j).
static __device__ __forceinline__ i32x8 prod_fp4_to_fp8(int4 a, int4 b) {
    const unsigned* aw = (const unsigned*)&a;
    const unsigned* bw = (const unsigned*)&b;
    i32x8 r;
#pragma unroll
    for (int i = 0; i < 4; i++) {
        unsigned av = aw[i], bv = bw[i];
#if HW_FP4_DEC
        f32x2 p0 = __builtin_amdgcn_cvt_scalef32_pk_f32_fp4(av, 1.0f, 0)
                 * __builtin_amdgcn_cvt_scalef32_pk_f32_fp4(bv, 1.0f, 0);
        f32x2 p1 = __builtin_amdgcn_cvt_scalef32_pk_f32_fp4(av, 1.0f, 1)
                 * __builtin_amdgcn_cvt_scalef32_pk_f32_fp4(bv, 1.0f, 1);
        f32x2 p2 = __builtin_amdgcn_cvt_scalef32_pk_f32_fp4(av, 1.0f, 2)
                 * __builtin_amdgcn_cvt_scalef32_pk_f32_fp4(bv, 1.0f, 2);
        f32x2 p3 = __builtin_amdgcn_cvt_scalef32_pk_f32_fp4(av, 1.0f, 3)
                 * __builtin_amdgcn_cvt_scalef32_pk_f32_fp4(bv, 1.0f, 3);
        r[2*i]   = (int)pk4_fp8(p0.x, p0.y, p1.x, p1.y);
        r[2*i+1] = (int)pk4_fp8(p2.x, p2.y, p3.x, p3.y);
#else
        float p[8];
#pragma unroll
        for (int j = 0; j < 8; j++)
            p[j] = dec_fp4((av >> (4*j)) & 0xF) * dec_fp4((bv >> (4*j)) & 0xF);
        r[2*i]   = (int)pk4_fp8(p[0], p[1], p[2], p[3]);
        r[2*i+1] = (int)pk4_fp8(p[4], p[5], p[6], p[7]);
#endif
    }
    return r;
}

// 32-byte (8-dword) load as two dwordx4
static __device__ __forceinline__ i32x8 ld32(const unsigned char* p) {
    int4 lo = *(const int4*)p;
    int4 hi = *(const int4*)(p + 16);
    i32x8 v;
    v[0] = lo.x; v[1] = lo.y; v[2] = lo.z; v[3] = lo.w;
    v[4] = hi.x; v[5] = hi.y; v[6] = hi.z; v[7] = hi.w;
    return v;
}

// 16-byte fp4 fragment into low half of an i32x8 A/B operand (fp4 uses 4 regs)
static __device__ __forceinline__ i32x8 lo4(int4 v) {
    i32x8 r;
    r[0] = v.x; r[1] = v.y; r[2] = v.z; r[3] = v.w;
    r[4] = 0; r[5] = 0; r[6] = 0; r[7] = 0;
    return r;
}

// FMT codes: 0=fp8(e4m3), 4=fp4(e2m1). unit e8m0 scales (0x7F per byte).
#define MFMA_F4(A, B, C) __builtin_amdgcn_mfma_scale_f32_16x16x128_f8f6f4( \
                             (A), (B), (C), 4, 4, 0, 0x7F7F7F7F, 0, 0x7F7F7F7F)
#define MFMA_F8(A, B, C) __builtin_amdgcn_mfma_scale_f32_16x16x128_f8f6f4( \
                             (A), (B), (C), 0, 0, 0, 0x7F7F7F7F, 0, 0x7F7F7F7F)

// ---------------------------------------------------------------------------
// Kernel 0: wsum[r] = sum_d W[r][d], f32, 32 blocks x 4 rows (wave per row).
// (einsum 'ed,ef->e' factorizes EXACTLY: bilinear[e] = (z_src.wsum)*(sum z_dst))
// ---------------------------------------------------------------------------
__global__ __launch_bounds__(256) void wsum_kernel(const float* __restrict__ W,
                                                   float* __restrict__ wsum)
{
    const int wv = threadIdx.x >> 6, lane = threadIdx.x & 63;
    const int r = blockIdx.x * 4 + wv;            // 0..127
    float2 v = *(const float2*)(W + (size_t)r * DIM + lane * 2);
    float s = v.x + v.y;
    s += __shfl_xor(s, 1);  s += __shfl_xor(s, 2);  s += __shfl_xor(s, 4);
    s += __shfl_xor(s, 8);  s += __shfl_xor(s, 16); s += __shfl_xor(s, 32);
    if (lane == 0) wsum[r] = s;
}

// ---------------------------------------------------------------------------
// Kernel 1 prep:
//  blocks [0,nNodeBlk): half-wave per node — zb4[n] = fp4(z[n]) (64 B/row),
//    s1[n] = z.wsum (f32), s2[n] = sum z (f32)   [bilinear stays full f32]
//  blocks [nNodeBlk, +48):  w1T8[h][k] = fp8(w1[k][h])  (chunk-2 B operand)
//  blocks [nNodeBlk+48,+24): w1T4[h][k-pairs] = fp4(w1) (chunks 0/1 B operand)
// ---------------------------------------------------------------------------
__global__ __launch_bounds__(256) void prep_kernel(
    const float* __restrict__ z, const float* __restrict__ w1,
    const float* __restrict__ wsum,
    unsigned char* __restrict__ zb4, unsigned char* __restrict__ w1T8,
    unsigned char* __restrict__ w1T4,
    float* __restrict__ s1, float* __restrict__ s2,
    int nNodes, int nNodeBlk)
{
    const int b = blockIdx.x;
    const int tid = threadIdx.x;
    if (b < nNodeBlk) {
        const int n = b * 8 + (tid >> 5);
        const int l32 = tid & 31;
        if (n >= nNodes) return;                   // half-wave-uniform exit

        float4 v = *(const float4*)(z + (size_t)n * DIM + l32 * 4);
        float4 w = *(const float4*)(wsum + l32 * 4);

        float a1 = v.x * w.x + v.y * w.y + v.z * w.z + v.w * w.w;
        float a2 = v.x + v.y + v.z + v.w;

        // fp4 pack: 4 elems -> 2 bytes, k ascending, low nibble first
        unsigned b0 = enc_fp4(v.x) | (enc_fp4(v.y) << 4);
        unsigned b1 = enc_fp4(v.z) | (enc_fp4(v.w) << 4);
        *(unsigned short*)(zb4 + (size_t)n * 64 + l32 * 2) =
            (unsigned short)(b0 | (b1 << 8));

        a1 += __shfl_xor(a1, 1);  a1 += __shfl_xor(a1, 2);  a1 += __shfl_xor(a1, 4);
        a1 += __shfl_xor(a1, 8);  a1 += __shfl_xor(a1, 16);
        a2 += __shfl_xor(a2, 1);  a2 += __shfl_xor(a2, 2);  a2 += __shfl_xor(a2, 4);
        a2 += __shfl_xor(a2, 8);  a2 += __shfl_xor(a2, 16);
        if (l32 == 0) { s1[n] = a1; s2[n] = a2; }
    } else if (b < nNodeBlk + 48) {
        const int idx = (b - nNodeBlk) * 256 + tid;    // 0..12287 exact
        const int k = idx >> 5, h = idx & 31;
        unsigned r = __builtin_amdgcn_cvt_pk_fp8_f32(w1[idx], 0.f, 0u, false);
        w1T8[(size_t)h * KTOT + k] = (unsigned char)(r & 0xff);
    } else {
        const int idx2 = (b - nNodeBlk - 48) * 256 + tid;  // 0..6143 exact
        const int k2 = idx2 >> 5, h = idx2 & 31;           // k2: byte (2 k's)
        float va = w1[(2 * k2) * 32 + h];
        float vb = w1[(2 * k2 + 1) * 32 + h];
        w1T4[(size_t)h * (KTOT / 2) + k2] =
            (unsigned char)(enc_fp4(va) | (enc_fp4(vb) << 4));
    }
}

// ---------------------------------------------------------------------------
// Kernel 2: edge kernel. R12: fp4 node rows (64 B) — working set 6.4 MB
// (L2-hit-friendly), random L3 line traffic halved. Chunks 0/1: A=fp4,B=fp4
// (same-format both sides => lane k-enumeration cancels, permutation-safe,
// same argument that validated the all-fp8 kernel). Chunk 2: product computed
// f32 from fp4 decodes, packed fp8, A=fp8 x B=fp8 (validated path).
// Bilinear stays f32 via s1/s2. Epilogue layout validated R3..R8.
// ---------------------------------------------------------------------------
__global__ __launch_bounds__(256, 2) void edge_kernel(
    const unsigned char* __restrict__ zb4, const int* __restrict__ ei,
    const float* __restrict__ s1, const float* __restrict__ s2,
    const unsigned char* __restrict__ w1T8, const unsigned char* __restrict__ w1T4,
    const float* __restrict__ b1,
    const float* __restrict__ w2, const float* __restrict__ b2,
    const float* __restrict__ bias, float* __restrict__ out,
    int nE, int nTiles)
{
    const int lane = threadIdx.x & 63;
    const int wv   = threadIdx.x >> 6;
    const int l15  = lane & 15;
    const int quad = lane >> 4;

    int t = blockIdx.x * 4 + wv;
    const int nW = gridDim.x * 4;
    if (t >= nTiles) return;

    // B fragments. fp4 rows: 192 B per h; lane (l15=h-col, quad) takes 16 B
    // at quad*16 within each 64-B K-chunk. fp8 chunk-2: 32 B at 256+quad*32.
    i32x8 B0c0, B0c1, B1c0, B1c1, B0c2, B1c2;
    {
        const unsigned char* p0 = w1T4 + (size_t)l15 * (KTOT / 2) + quad * 16;
        const unsigned char* p1 = w1T4 + (size_t)(16 + l15) * (KTOT / 2) + quad * 16;
        B0c0 = lo4(*(const int4*)(p0));
        B0c1 = lo4(*(const int4*)(p0 + 64));
        B1c0 = lo4(*(const int4*)(p1));
        B1c1 = lo4(*(const int4*)(p1 + 64));
        B0c2 = ld32(w1T8 + (size_t)l15 * KTOT + 256 + quad * 32);
        B1c2 = ld32(w1T8 + (size_t)(16 + l15) * KTOT + 256 + quad * 32);
    }
    const float b1a = b1[l15],      w2a = w2[l15];
    const float b1b = b1[16 + l15], w2b = w2[16 + l15];
    const float cbias = bias[0] + b2[0];

    for (; t < nTiles; t += nW) {
        const int e = t * TPW + l15;
        int s_ = 0, d_ = 0;
        if (e < nE) { s_ = ei[e]; d_ = ei[nE + e]; }
        const float bil = s1[s_] * s2[d_];         // f32 path, lane l15 = edge l15

        // fp4 row gathers: ONE dwordx4 per row (16 B at quad*16)
        int4 zs4 = *(const int4*)(zb4 + (size_t)s_ * 64 + quad * 16);
        int4 zd4 = *(const int4*)(zb4 + (size_t)d_ * 64 + quad * 16);

        f32x4 acc0 = {0.f, 0.f, 0.f, 0.f};
        f32x4 acc1 = {0.f, 0.f, 0.f, 0.f};
        // chunk 0: zs (K 0..127), fp4 x fp4
        i32x8 zsA = lo4(zs4), zdA = lo4(zd4);
        acc0 = MFMA_F4(zsA, B0c0, acc0);
        acc1 = MFMA_F4(zsA, B1c0, acc1);
        // chunk 1: zd (K 128..255), fp4 x fp4
        acc0 = MFMA_F4(zdA, B0c1, acc0);
        acc1 = MFMA_F4(zdA, B1c1, acc1);
        // chunk 2: zs*zd (K 256..383), product in f32 -> fp8, fp8 x fp8
        i32x8 p8 = prod_fp4_to_fp8(zs4, zd4);
        acc0 = MFMA_F8(p8, B0c2, acc0);
        acc1 = MFMA_F8(p8, B1c2, acc1);

        // epilogue (validated R3..R8): C/D col=l15 (h), row=quad*4+r (edge)
        const int e0 = t * TPW;
#pragma unroll
        for (int r = 0; r < 4; r++) {
            float v = fmaxf(acc0[r] + b1a, 0.f) * w2a
                    + fmaxf(acc1[r] + b1b, 0.f) * w2b;
            v += __shfl_xor(v, 1); v += __shfl_xor(v, 2);
            v += __shfl_xor(v, 4); v += __shfl_xor(v, 8);
            const int eL = quad * 4 + r;
            const float bilr = __shfl(bil, eL);    // bil replicated across quads
            if (l15 == r && (e0 + eL) < nE)
                out[e0 + eL] = v + bilr + cbias;
        }
    }
}

// ---------------------------------------------------------------------------
// Workspace: zb4 uchar[nNodes*64] | s1 f32[nNodes] | s2 f32[nNodes]
//          | wsum f32[128] | w1T8 uchar[32*384] | w1T4 uchar[32*192] (~7.2 MB)
// ---------------------------------------------------------------------------
extern "C" void kernel_launch(void* const* d_in, const int* in_sizes, int n_in,
                              void* d_out, int out_size, void* d_ws, size_t ws_size,
                              hipStream_t stream)
{
    const float* z    = (const float*)d_in[0];
    const int*   ei   = (const int*)d_in[1];
    const float* W    = (const float*)d_in[2];
    const float* bias = (const float*)d_in[3];
    const float* w1   = (const float*)d_in[4];
    const float* b1   = (const float*)d_in[5];
    const float* w2   = (const float*)d_in[6];
    const float* b2   = (const float*)d_in[7];
    float* out = (float*)d_out;

    const int nNodes = in_sizes[0] / DIM;
    const int nE = out_size;

    unsigned char* zb4 = (unsigned char*)d_ws;
    float* s1   = (float*)(zb4 + (size_t)nNodes * 64);
    float* s2   = s1 + nNodes;
    float* wsum = s2 + nNodes;
    unsigned char* w1T8 = (unsigned char*)(wsum + DIM);
    unsigned char* w1T4 = w1T8 + (size_t)HID * KTOT;

    wsum_kernel<<<32, 256, 0, stream>>>(W, wsum);

    const int nNodeBlk = (nNodes + 7) / 8;
    prep_kernel<<<nNodeBlk + 48 + 24, 256, 0, stream>>>(z, w1, wsum, zb4, w1T8,
                                                        w1T4, s1, s2,
                                                        nNodes, nNodeBlk);

    const int nTiles = (nE + TPW - 1) / TPW;
    int grid = 1024;
    if (grid * 4 > nTiles) grid = (nTiles + 3) / 4;
    edge_kernel<<<grid, 256, 0, stream>>>(zb4, ei, s1, s2, w1T8, w1T4,
                                          b1, w2, b2, bias, out, nE, nTiles);
}